// Round 2
// baseline (1575.595 us; speedup 1.0000x reference)
//
#include <hip/hip_runtime.h>

#define NT 128      // num tags
#define SEQ 1024    // sequence length
#define NB 256      // batch

// ONE WAVE per batch element. 256 blocks x 64 threads.
// Lane l owns output columns c0=2l, c1=2l+1 and keeps both full E columns
// (prob domain, fp32) in registers: 256 VGPRs. At 1 wave/SIMD this is legal
// (no-spill budget ~450+). No __syncthreads anywhere in the scan: the only
// cross-lane traffic is the p vector through wave-private LDS, and per-wave
// DS ops are processed in order (compiler inserts lgkmcnt).
__global__ __launch_bounds__(64) void crf_scan_kernel(
    const float* __restrict__ emissions,    // [B,S,T]
    const float* __restrict__ masks,        // [B,S]
    const int*   __restrict__ tags,         // [B,S]
    const float* __restrict__ transitions,  // [T,T] (log domain)
    const float* __restrict__ start_t,      // [T]
    const float* __restrict__ end_t,        // [T]
    float* __restrict__ out_per_batch)      // [B]
{
    const int b  = blockIdx.x;
    const int l  = threadIdx.x;          // 0..63
    const int c0 = 2 * l;
    const int c1 = 2 * l + 1;

    __shared__ float p_s[NT];            // scaled probabilities (max-normalized every 4 steps)
    __shared__ float msk_s[SEQ];

    // ---- E columns into registers (prob domain) ----
    float2 E2[NT];                       // E2[i] = {exp(T[i][c0]), exp(T[i][c1])}
    #pragma unroll
    for (int i = 0; i < NT; ++i) {
        float2 tv = *(const float2*)&transitions[i * NT + c0];
        E2[i].x = __expf(tv.x);
        E2[i].y = __expf(tv.y);
    }

    // masks into LDS (written and read by the same wave -> no barrier needed)
    for (int s = l; s < SEQ; s += 64)
        msk_s[s] = masks[b * SEQ + s];

    // ---- init: p = exp(start_transitions), offset = 0 ----
    float cur0 = __expf(start_t[c0]);
    float cur1 = __expf(start_t[c1]);
    *(float2*)&p_s[c0] = make_float2(cur0, cur1);
    float offset = 0.0f;

    const float* eb = emissions + (size_t)b * SEQ * NT;

    // emission pipeline: ex = exp(em[s]) ready, em1 = raw em[s+1], prefetch s+2
    float2 em0 = *(const float2*)&eb[(size_t)0 * NT + c0];
    float2 em1 = *(const float2*)&eb[(size_t)1 * NT + c0];
    float2 ex;
    ex.x = __expf(em0.x);
    ex.y = __expf(em0.y);

    const float4* p4 = (const float4*)p_s;

    for (int s = 0; s < SEQ; ++s) {
        // prefetch emission 2 steps ahead (covers HBM latency)
        int spre = (s + 2 < SEQ) ? s + 2 : SEQ - 1;
        float2 em2 = *(const float2*)&eb[(size_t)spre * NT + c0];

        // matvec: v_j = sum_i p_i * E[i][j], two columns per lane.
        // p read as all-lanes-same-address float4 broadcasts (conflict-free);
        // float2 accumulators bait v_pk_fma_f32.
        float2 a0 = {0.f, 0.f}, a1 = {0.f, 0.f}, a2 = {0.f, 0.f}, a3 = {0.f, 0.f};
        #pragma unroll
        for (int c = 0; c < 32; ++c) {
            float4 pv = p4[c];
            a0.x += pv.x * E2[4*c+0].x;  a0.y += pv.x * E2[4*c+0].y;
            a1.x += pv.y * E2[4*c+1].x;  a1.y += pv.y * E2[4*c+1].y;
            a2.x += pv.z * E2[4*c+2].x;  a2.y += pv.z * E2[4*c+2].y;
            a3.x += pv.w * E2[4*c+3].x;  a3.y += pv.w * E2[4*c+3].y;
        }
        float v0 = ((a0.x + a1.x) + (a2.x + a3.x)) * ex.x;
        float v1 = ((a0.y + a1.y) + (a2.y + a3.y)) * ex.y;

        bool upd = msk_s[s] > 0.0f;      // wave-uniform
        if (upd) { cur0 = v0; cur1 = v1; }

        // deferred renormalization: every 4 steps (overflow-safe, see analysis)
        if ((s & 3) == 3) {
            float m = fmaxf(cur0, cur1);
            #pragma unroll
            for (int off = 32; off; off >>= 1)
                m = fmaxf(m, __shfl_xor(m, off));
            float inv = 1.0f / m;
            cur0 *= inv; cur1 *= inv;
            offset += __logf(m);         // identity-preserving regardless of mask
        }
        *(float2*)&p_s[c0] = make_float2(cur0, cur1);

        // rotate emission pipeline (exp computed off the critical path)
        ex.x = __expf(em1.x);
        ex.y = __expf(em1.y);
        em1 = em2;
    }

    // ---- log_z = offset + log( sum_j p_j * exp(end_j) ) ----
    float term = cur0 * __expf(end_t[c0]) + cur1 * __expf(end_t[c1]);
    #pragma unroll
    for (int off = 32; off; off >>= 1)
        term += __shfl_xor(term, off);
    float log_z = offset + __logf(term);

    // ---- gold-path score (single wave, 16 s-iters/lane) ----
    const int tb = b * SEQ;
    float sc = 0.0f, sm = 0.0f;
    for (int s = l; s < SEQ; s += 64) {
        float m = msk_s[s];
        sm += m;
        if (s < SEQ - 1) {
            int tg  = tags[tb + s];
            int tg1 = tags[tb + s + 1];
            sc += eb[(size_t)s * NT + tg] * m;
            sc += transitions[tg * NT + tg1] * msk_s[s + 1];
        }
    }
    #pragma unroll
    for (int off = 32; off; off >>= 1) {
        sc += __shfl_xor(sc, off);
        sm += __shfl_xor(sm, off);
    }

    if (l == 0) {
        int tg0 = tags[tb];
        int tgl = tags[tb + SEQ - 1];
        sc += start_t[tg0];
        int last_ix = (int)fmaxf(sm - 1.0f, 0.0f);
        float ml = msk_s[SEQ - 1];
        sc += eb[(size_t)last_ix * NT + tgl] * ml;
        sc += end_t[tgl] * ml;
        out_per_batch[b] = log_z - sc;
    }
}

// mean over batch -> scalar output
__global__ void crf_reduce_kernel(const float* __restrict__ pb, float* __restrict__ out)
{
    float v = pb[threadIdx.x];   // 256 threads, one per batch
    #pragma unroll
    for (int off = 32; off; off >>= 1)
        v += __shfl_xor(v, off);
    __shared__ float s4[4];
    if ((threadIdx.x & 63) == 0) s4[threadIdx.x >> 6] = v;
    __syncthreads();
    if (threadIdx.x == 0)
        out[0] = (s4[0] + s4[1] + s4[2] + s4[3]) * (1.0f / 256.0f);
}

extern "C" void kernel_launch(void* const* d_in, const int* in_sizes, int n_in,
                              void* d_out, int out_size, void* d_ws, size_t ws_size,
                              hipStream_t stream) {
    const float* emissions   = (const float*)d_in[0];
    const float* masks       = (const float*)d_in[1];
    const int*   tags        = (const int*)  d_in[2];
    const float* transitions = (const float*)d_in[3];
    const float* start_t     = (const float*)d_in[4];
    const float* end_t       = (const float*)d_in[5];
    float* per_batch = (float*)d_ws;

    crf_scan_kernel<<<NB, 64, 0, stream>>>(emissions, masks, tags, transitions,
                                           start_t, end_t, per_batch);
    crf_reduce_kernel<<<1, 256, 0, stream>>>(per_batch, (float*)d_out);
}